// Round 7
// baseline (404.859 us; speedup 1.0000x reference)
//
#include <hip/hip_runtime.h>

#define N_NODES 50000
#define N_EDGES 800000
#define BATCH   32
#define NWORD8  12500   // N_NODES/4 u32 words (u8-packed deg counts / qd8 table)
#define NWORDC  25000   // N_NODES/2 u32 words, u16-packed c (full range, 100 KB)
#define CHUNKS  8       // edge chunks for hist AND cscat (100K edges each)
#define EPC4    25000   // int4 edge loads per chunk (= 100000 edges)
#define QSCALE  255.0f
#define PTHREADS 640    // pool threads: 640*4 % 10 == 0 keeps per-lane phase const

// Pipeline (4 launches): K1 hist -> K3 cscat -> K4 pool -> K5 mlp.
// The old K2 (dinv/qd8 bridge) is eliminated: K3 rebuilds the u8 qd8 table
// in LDS from the degree partials, K4 rebuilds f32 dinv per node-pair in its
// wlds loop. Both recompute rsqrtf on the SAME exact integer degrees ->
// bit-identical results, two fewer global round-trips, one fewer launch.
// XCD-locality: every kernel maps batch b so blocks satisfy id%8 == b&7.

// ---------------------------------------------------------------------------
// K1: per-(batch,chunk) degree histogram in LDS (u8 packed x4 per u32 word).
// grid (32, 8): b = blockIdx.x -> id%8 == b&7 (partials stay in local L2).
// Per-chunk degree is Binomial(100K, 1/50K): mean 2, P(>255) ~ 0 -> u8 safe.
// ---------------------------------------------------------------------------
__global__ __launch_bounds__(1024) void hist_kernel(const int* __restrict__ ei,
                                                    unsigned* __restrict__ hpart) {
    const int b = blockIdx.x, chunk = blockIdx.y;   // grid (32, 8)
    __shared__ unsigned cnt[NWORD8];  // 50 KB
    for (int i = threadIdx.x; i < NWORD8; i += 1024) cnt[i] = 0;
    __syncthreads();
    const int4* __restrict__ dst4 =
        (const int4*)(ei + (size_t)b * (2 * N_EDGES) + N_EDGES) + (size_t)chunk * EPC4;
    for (int i = threadIdx.x; i < EPC4; i += 1024) {
        const int4 v = dst4[i];
        atomicAdd(&cnt[((unsigned)v.x) >> 2], 1u << ((v.x & 3) * 8));
        atomicAdd(&cnt[((unsigned)v.y) >> 2], 1u << ((v.y & 3) * 8));
        atomicAdd(&cnt[((unsigned)v.z) >> 2], 1u << ((v.z & 3) * 8));
        atomicAdd(&cnt[((unsigned)v.w) >> 2], 1u << ((v.w & 3) * 8));
    }
    __syncthreads();
    unsigned* __restrict__ out = hpart + (size_t)(b * CHUNKS + chunk) * NWORD8;
    for (int i = threadIdx.x; i < NWORD8; i += 1024) out[i] = cnt[i];
}

// ---------------------------------------------------------------------------
// K3: c[n] = sum over out-edges of n of dinv[dst], u16 fixed-point histogram
// over the FULL node range. The u8 dinv gather table is built IN LDS directly
// from the degree partials (folds old K2's qd8 path): 8 strided L2-local
// loads + 4 rsqrt per u32 word, ~12 words/thread. Random gather stays a
// ds_read_u8. Dynamic LDS = 100 KB histogram + 50 KB table; 256 blocks=1/CU.
// id%8 == b&7 (b = (id&7) + 8*bgroup): hpart[b] read / cpart[b] written local.
// ---------------------------------------------------------------------------
__global__ __launch_bounds__(1024) void cscat_kernel(const int* __restrict__ ei,
                                                     const unsigned* __restrict__ hpart,
                                                     unsigned* __restrict__ cpart) {
    extern __shared__ unsigned smem[];           // [0,25000): cs, [25000,37500): qd8
    unsigned* cs = smem;
    unsigned* qtab = smem + NWORDC;
    const unsigned char* qs = (const unsigned char*)qtab;
    const int id = blockIdx.x;  // 256 = 8 xcd * 4 bgroup * 8 chunk
    const int b = (id & 7) + 8 * ((id >> 3) & 3);
    const int chunk = id >> 5;
    for (int i = threadIdx.x; i < NWORDC; i += 1024) cs[i] = 0;
    {   // build the batch's u8 dinv table from degree partials (was K2 + stage)
        const unsigned* __restrict__ p = hpart + (size_t)(b * CHUNKS) * NWORD8;
        for (int i = threadIdx.x; i < NWORD8; i += 1024) {
            unsigned d0 = 0, d1 = 0, d2 = 0, d3 = 0;
#pragma unroll
            for (int c2 = 0; c2 < CHUNKS; ++c2) {
                const unsigned v = p[(size_t)c2 * NWORD8 + i];
                d0 += v & 0xFF; d1 += (v >> 8) & 0xFF; d2 += (v >> 16) & 0xFF; d3 += v >> 24;
            }
            const unsigned q0 = __float2uint_rn(rsqrtf((float)(d0 + 1)) * QSCALE);
            const unsigned q1 = __float2uint_rn(rsqrtf((float)(d1 + 1)) * QSCALE);
            const unsigned q2 = __float2uint_rn(rsqrtf((float)(d2 + 1)) * QSCALE);
            const unsigned q3 = __float2uint_rn(rsqrtf((float)(d3 + 1)) * QSCALE);
            qtab[i] = q0 | (q1 << 8) | (q2 << 16) | (q3 << 24);
        }
    }
    __syncthreads();
    const int* eb = ei + (size_t)b * (2 * N_EDGES);
    const int4* __restrict__ src4 = (const int4*)eb + (size_t)chunk * EPC4;
    const int4* __restrict__ dst4 = (const int4*)(eb + N_EDGES) + (size_t)chunk * EPC4;
    for (int i = threadIdx.x; i < EPC4; i += 1024) {
        const int4 s4 = src4[i];
        const int4 d4 = dst4[i];
        const unsigned q0 = qs[d4.x];
        const unsigned q1 = qs[d4.y];
        const unsigned q2 = qs[d4.z];
        const unsigned q3 = qs[d4.w];
        atomicAdd(&cs[((unsigned)s4.x) >> 1], q0 << ((s4.x & 1) << 4));
        atomicAdd(&cs[((unsigned)s4.y) >> 1], q1 << ((s4.y & 1) << 4));
        atomicAdd(&cs[((unsigned)s4.z) >> 1], q2 << ((s4.z & 1) << 4));
        atomicAdd(&cs[((unsigned)s4.w) >> 1], q3 << ((s4.w & 1) << 4));
    }
    __syncthreads();
    unsigned* __restrict__ out = cpart + (size_t)(b * CHUNKS + chunk) * NWORDC;
    for (int i = threadIdx.x; i < NWORDC; i += 1024) out[i] = cs[i];
}

// ---------------------------------------------------------------------------
// K4: fused dinv + w + pool. grid (32, 8): id%8 == b&7 (hpart/cpart local).
// Block (b,c) owns nodes [c*6250,(c+1)*6250): per node-pair, reduce 8 cpart
// chunks (c) AND 8 hpart chunks (degree -> f32 rsqrt, folds old K2's dinv),
// then w = dinv*(c+dinv) -> wlds in LDS. Pooled weighted column-sum follows
// (float4, 640 threads, fixed channel phase, ln += 256 strength reduction).
// ---------------------------------------------------------------------------
__global__ __launch_bounds__(PTHREADS) void pool_kernel(const unsigned* __restrict__ cpart,
                                                        const unsigned* __restrict__ hpart,
                                                        const float* __restrict__ xg,
                                                        float* __restrict__ spart) {
    const int b = blockIdx.x, chunk = blockIdx.y;  // grid (32, 8)
    __shared__ float wlds[6250];                   // 25 KB w-slice
    __shared__ float sacc[PTHREADS / 64][10];
    const int tid = threadIdx.x;

    // ---- w-slice: w[n] = dinv*(c+dinv) for this block's 6250 nodes ----
    const int wbase = chunk * (NWORDC / 8);        // 3125 u16-pair words
    for (int li = tid; li < NWORDC / 8; li += PTHREADS) {
        const int gw = wbase + li;                 // node pair n = 2*gw, n+1
        const int pw = gw >> 1;                    // hpart u8x4 word (4 nodes)
        const int hi = gw & 1;                     // which half of that word
        const unsigned* __restrict__ pc = cpart + (size_t)(b * CHUNKS) * NWORDC + gw;
        const unsigned* __restrict__ pd = hpart + (size_t)(b * CHUNKS) * NWORD8 + pw;
        unsigned c0 = 0, c1 = 0, d0 = 0, d1 = 0;
#pragma unroll
        for (int ch = 0; ch < CHUNKS; ++ch) {
            const unsigned v = pc[(size_t)ch * NWORDC];
            c0 += v & 0xFFFF; c1 += v >> 16;
            const unsigned u = pd[(size_t)ch * NWORD8];
            d0 += (u >> (16 * hi)) & 0xFF;
            d1 += (u >> (16 * hi + 8)) & 0xFF;
        }
        const float dx = rsqrtf((float)(d0 + 1));
        const float dy = rsqrtf((float)(d1 + 1));
        wlds[2 * li]     = dx * ((float)c0 * (1.0f / QSCALE) + dx);
        wlds[2 * li + 1] = dy * ((float)c1 * (1.0f / QSCALE) + dy);
    }
    const int wave = tid >> 6;
    if ((tid & 63) < 10) sacc[wave][tid & 63] = 0.0f;
    __syncthreads();

    // ---- pooled weighted column-sum from LDS w ----
    const float4* __restrict__ xg4 = (const float4*)xg;
    const int base4 = b * 125000 + chunk * 15625;  // float4 index; 4*base4 % 10 == 0
    const int r = (4 * tid) % 10;                  // element phase, fixed per lane
    int ln = (4 * tid) / 10;                       // local node; +256 per iteration
    float a0 = 0.0f, a1 = 0.0f, a2 = 0.0f, a3 = 0.0f;
    for (int j = tid; j < 15625; j += PTHREADS, ln += 256) {
        const float4 v = xg4[base4 + j];
        const float w0 = wlds[ln];
        const float w1 = (r == 8) ? wlds[ln + 1] : w0;  // r==8: z,w cross node boundary
        a0 += v.x * w0;
        a1 += v.y * w0;
        a2 += v.z * w1;
        a3 += v.w * w1;
    }
    atomicAdd(&sacc[wave][r], a0);
    atomicAdd(&sacc[wave][(r + 1) % 10], a1);
    atomicAdd(&sacc[wave][(r + 2) % 10], a2);
    atomicAdd(&sacc[wave][(r + 3) % 10], a3);
    __syncthreads();
    if (tid < 10) {
        float v = 0.0f;
#pragma unroll
        for (int wv = 0; wv < PTHREADS / 64; ++wv) v += sacc[wv][tid];
        spart[(b * CHUNKS + chunk) * 16 + tid] = v;
    }
}

// ---------------------------------------------------------------------------
// K5: reduce pool partials + tiny MLP + log_softmax(axis=0). One block.
// ---------------------------------------------------------------------------
__global__ __launch_bounds__(512) void mlp_kernel(const float* __restrict__ spart,
                           const float* __restrict__ x,
                           const float* __restrict__ W_gcn,
                           const float* __restrict__ b_gcn,
                           const float* __restrict__ W1, const float* __restrict__ b1,
                           const float* __restrict__ W2, const float* __restrict__ b2,
                           const float* __restrict__ Wo, const float* __restrict__ bo,
                           float* __restrict__ out) {
    __shared__ float ssum[32][10];
    __shared__ float h0[32][20];
    __shared__ float h1[32][80];
    __shared__ float h2[32][160];
    __shared__ float o[32][4];
    const int tid = threadIdx.x;

    for (int idx = tid; idx < 32 * 10; idx += blockDim.x) {
        const int b = idx / 10, k = idx % 10;
        float v = 0.0f;
#pragma unroll
        for (int c = 0; c < CHUNKS; ++c) v += spart[(b * CHUNKS + c) * 16 + k];
        ssum[b][k] = v;
    }
    __syncthreads();

    for (int idx = tid; idx < 32 * 20; idx += blockDim.x) {
        const int b = idx / 20, j = idx % 20;
        float v;
        if (j < 10) {
            v = 0.0f;
#pragma unroll
            for (int k = 0; k < 10; ++k) v += ssum[b][k] * W_gcn[k * 10 + j];
            v = v * (1.0f / (float)N_NODES) + b_gcn[j];
        } else {
            v = x[b * 10 + (j - 10)];
        }
        h0[b][j] = v;
    }
    __syncthreads();

    for (int idx = tid; idx < 32 * 80; idx += blockDim.x) {
        const int b = idx / 80, j = idx % 80;
        float v = b1[j];
#pragma unroll
        for (int k = 0; k < 20; ++k) v += h0[b][k] * W1[k * 80 + j];
        h1[b][j] = (v > 0.0f) ? v : 0.01f * v;
    }
    __syncthreads();

    for (int idx = tid; idx < 32 * 160; idx += blockDim.x) {
        const int b = idx / 160, j = idx % 160;
        float v = b2[j];
        for (int k = 0; k < 80; ++k) v += h1[b][k] * W2[k * 160 + j];
        h2[b][j] = (v > 0.0f) ? v : 0.01f * v;
    }
    __syncthreads();

    for (int idx = tid; idx < 32 * 4; idx += blockDim.x) {
        const int b = idx / 4, j = idx % 4;
        float v = bo[j];
        for (int k = 0; k < 160; ++k) v += h2[b][k] * Wo[k * 4 + j];
        o[b][j] = v;
    }
    __syncthreads();

    if (tid < 4) {
        float m = -1e30f;
        for (int b = 0; b < 32; ++b) m = fmaxf(m, o[b][tid]);
        float lse = 0.0f;
        for (int b = 0; b < 32; ++b) lse += expf(o[b][tid] - m);
        lse = logf(lse);
        for (int b = 0; b < 32; ++b) out[b * 4 + tid] = o[b][tid] - m - lse;
    }
}

extern "C" void kernel_launch(void* const* d_in, const int* in_sizes, int n_in,
                              void* d_out, int out_size, void* d_ws, size_t ws_size,
                              hipStream_t stream) {
    (void)in_sizes; (void)n_in; (void)out_size; (void)ws_size;
    const float* x      = (const float*)d_in[0];
    const float* gcn_x  = (const float*)d_in[1];
    const int*   ei     = (const int*)d_in[2];
    const float* W_gcn  = (const float*)d_in[3];
    const float* b_gcn  = (const float*)d_in[4];
    const float* W1     = (const float*)d_in[5];
    const float* b1     = (const float*)d_in[6];
    const float* W2     = (const float*)d_in[7];
    const float* b2     = (const float*)d_in[8];
    const float* Wo     = (const float*)d_in[9];
    const float* bo     = (const float*)d_in[10];
    float* out = (float*)d_out;

    // workspace layout (offsets in bytes) - hpart must survive through K4,
    // so cpart gets its own region (no more buffer reuse):
    //   hpart [32*8*12500 u32]  @ 0           (12.8 MB degree partials)
    //   cpart [32*8*25000 u32]  @ 12,800,000  (25.6 MB c partials)
    //   spart [32*8*16 f32]     @ 38,400,000  (16 KB)     total ~38.4 MB
    unsigned* hpart = (unsigned*)d_ws;
    unsigned* cpart = (unsigned*)((char*)d_ws + (size_t)BATCH * CHUNKS * NWORD8 * 4);
    float*    spart = (float*)((char*)cpart + (size_t)BATCH * CHUNKS * NWORDC * 4);

    // 150 KB dynamic LDS for c-histogram (100 KB) + u8 dinv table (50 KB)
    hipFuncSetAttribute((const void*)cscat_kernel,
                        hipFuncAttributeMaxDynamicSharedMemorySize,
                        (NWORDC + NWORD8) * 4);

    {   // K1: degree histograms, batch-major grid for XCD locality
        dim3 grid(BATCH, CHUNKS);
        hist_kernel<<<grid, 1024, 0, stream>>>(ei, hpart);
    }
    {   // K3: c-scatter; qd8 table built in LDS from hpart (K2 folded in)
        cscat_kernel<<<256, 1024, (NWORDC + NWORD8) * 4, stream>>>(ei, hpart, cpart);
    }
    {   // K4: fused dinv + w + pool, batch-major grid
        dim3 grid(BATCH, CHUNKS);
        pool_kernel<<<grid, PTHREADS, 0, stream>>>(cpart, hpart, gcn_x, spart);
    }
    mlp_kernel<<<1, 512, 0, stream>>>(spart, x, W_gcn, b_gcn, W1, b1, W2, b2, Wo, bo, out);
}

// Round 8
// 402.755 us; speedup vs baseline: 1.0052x; 1.0052x over previous
//
#include <hip/hip_runtime.h>

#define N_NODES 50000
#define N_EDGES 800000
#define BATCH   32
#define NWORD8  12500   // N_NODES/4 u32 words (u8-packed deg counts / qd8 table)
#define NWORDC  25000   // N_NODES/2 u32 words, u16-packed c (full range, 100 KB)
#define CHUNKS  8       // edge chunks for hist AND cscat (100K edges each)
#define EPC4    25000   // int4 edge loads per chunk (= 100000 edges)
#define QSCALE  255.0f
#define PTHREADS 640    // pool threads: 640*4 % 10 == 0 keeps per-lane phase const

// Champion structure (R6, 396.4 us): 5 launches, no cross-block sync.
// K1 hist -> K2 dinv/qd8 -> K3 cscat -> K4 (w+pool fused) -> K5 mlp.
// Verdicts from this session's ledger:
//  - device-wide grid.sync costs ~100us each on 8 XCDs (R1: +240us)
//  - per-block device-scope fences for last-block patterns regress (R3: +48us)
//  - de-amortizing K2's reduce into consumers regresses (R7: +8.5us)
//  - 8-chunk hist (-4.4), w-fold into 640-thread pool (-7.2): kept
// XCD-locality: every kernel maps batch b so blocks satisfy id%8 == b&7.

// ---------------------------------------------------------------------------
// K1: per-(batch,chunk) degree histogram in LDS (u8 packed x4 per u32 word).
// grid (32, 8): b = blockIdx.x -> id%8 == b&7 (partials stay in local L2).
// Per-chunk degree is Binomial(100K, 1/50K): mean 2, P(>255) ~ 0 -> u8 safe.
// ---------------------------------------------------------------------------
__global__ __launch_bounds__(1024) void hist_kernel(const int* __restrict__ ei,
                                                    unsigned* __restrict__ partials) {
    const int b = blockIdx.x, chunk = blockIdx.y;   // grid (32, 8)
    __shared__ unsigned cnt[NWORD8];  // 50 KB
    for (int i = threadIdx.x; i < NWORD8; i += 1024) cnt[i] = 0;
    __syncthreads();
    const int4* __restrict__ dst4 =
        (const int4*)(ei + (size_t)b * (2 * N_EDGES) + N_EDGES) + (size_t)chunk * EPC4;
    for (int i = threadIdx.x; i < EPC4; i += 1024) {
        const int4 v = dst4[i];
        atomicAdd(&cnt[((unsigned)v.x) >> 2], 1u << ((v.x & 3) * 8));
        atomicAdd(&cnt[((unsigned)v.y) >> 2], 1u << ((v.y & 3) * 8));
        atomicAdd(&cnt[((unsigned)v.z) >> 2], 1u << ((v.z & 3) * 8));
        atomicAdd(&cnt[((unsigned)v.w) >> 2], 1u << ((v.w & 3) * 8));
    }
    __syncthreads();
    unsigned* __restrict__ out = partials + (size_t)(b * CHUNKS + chunk) * NWORD8;
    for (int i = threadIdx.x; i < NWORD8; i += 1024) out[i] = cnt[i];
}

// ---------------------------------------------------------------------------
// K2: reduce degree partials -> dinv[b][n] = rsqrt(count+1) (f32)
//     and qd8 = round(dinv * 255) packed x4 per u32 (LDS gather table for K3).
// grid (32, 49): b = blockIdx.x -> id%8 == b&7: reads partials[b] from the
// local L2, writes dinv[b]/qd8[b] into it for K3/K4. Amortized ONCE per word
// (R7 showed folding this into consumers de-amortizes it 8x and regresses).
// ---------------------------------------------------------------------------
__global__ void dinv_kernel(const unsigned* __restrict__ partials,
                            float* __restrict__ dinv,
                            unsigned* __restrict__ qd8) {
    const int b = blockIdx.x;
    const int i = blockIdx.y * 256 + threadIdx.x;   // word index within batch
    if (i >= NWORD8) return;
    const unsigned* __restrict__ p = partials + (size_t)(b * CHUNKS) * NWORD8 + i;
    unsigned d0 = 0, d1 = 0, d2 = 0, d3 = 0;
#pragma unroll
    for (int c = 0; c < CHUNKS; ++c) {
        const unsigned v = p[(size_t)c * NWORD8];
        d0 += v & 0xFF; d1 += (v >> 8) & 0xFF; d2 += (v >> 16) & 0xFF; d3 += v >> 24;
    }
    const float i0 = rsqrtf((float)(d0 + 1));
    const float i1 = rsqrtf((float)(d1 + 1));
    const float i2 = rsqrtf((float)(d2 + 1));
    const float i3 = rsqrtf((float)(d3 + 1));
    float4* dv4 = (float4*)(dinv + (size_t)b * N_NODES) + i;
    *dv4 = make_float4(i0, i1, i2, i3);
    const unsigned q0 = __float2uint_rn(i0 * QSCALE);
    const unsigned q1 = __float2uint_rn(i1 * QSCALE);
    const unsigned q2 = __float2uint_rn(i2 * QSCALE);
    const unsigned q3 = __float2uint_rn(i3 * QSCALE);
    qd8[(size_t)b * NWORD8 + i] = q0 | (q1 << 8) | (q2 << 16) | (q3 << 24);
}

// ---------------------------------------------------------------------------
// K3: c[n] = sum over out-edges of n of dinv[dst], u16 fixed-point histogram
// over the FULL node range. dst-side dinv table lives in LDS as u8 (50 KB):
// the random gather is a ds_read_u8, not a divergent global load.
// Dynamic LDS = 100 KB histogram + 50 KB qd8 = 150 KB; 256 blocks = 1/CU.
// id%8 == b&7 already (b = (id&7) + 8*bgroup): cpart[b] lands in local L2.
// ---------------------------------------------------------------------------
__global__ __launch_bounds__(1024) void cscat_kernel(const int* __restrict__ ei,
                                                     const unsigned* __restrict__ qd8,
                                                     unsigned* __restrict__ cpart) {
    extern __shared__ unsigned smem[];           // [0,25000): cs, [25000,37500): qd8
    unsigned* cs = smem;
    const unsigned char* qs = (const unsigned char*)(smem + NWORDC);
    const int id = blockIdx.x;  // 256 = 8 xcd * 4 bgroup * 8 chunk
    const int b = (id & 7) + 8 * ((id >> 3) & 3);
    const int chunk = id >> 5;
    for (int i = threadIdx.x; i < NWORDC; i += 1024) cs[i] = 0;
    {   // stage the batch's u8 dinv table into LDS (coalesced, 50 KB)
        const unsigned* __restrict__ src = qd8 + (size_t)b * NWORD8;
        unsigned* dst = smem + NWORDC;
        for (int i = threadIdx.x; i < NWORD8; i += 1024) dst[i] = src[i];
    }
    __syncthreads();
    const int* eb = ei + (size_t)b * (2 * N_EDGES);
    const int4* __restrict__ src4 = (const int4*)eb + (size_t)chunk * EPC4;
    const int4* __restrict__ dst4 = (const int4*)(eb + N_EDGES) + (size_t)chunk * EPC4;
    for (int i = threadIdx.x; i < EPC4; i += 1024) {
        const int4 s4 = src4[i];
        const int4 d4 = dst4[i];
        const unsigned q0 = qs[d4.x];
        const unsigned q1 = qs[d4.y];
        const unsigned q2 = qs[d4.z];
        const unsigned q3 = qs[d4.w];
        atomicAdd(&cs[((unsigned)s4.x) >> 1], q0 << ((s4.x & 1) << 4));
        atomicAdd(&cs[((unsigned)s4.y) >> 1], q1 << ((s4.y & 1) << 4));
        atomicAdd(&cs[((unsigned)s4.z) >> 1], q2 << ((s4.z & 1) << 4));
        atomicAdd(&cs[((unsigned)s4.w) >> 1], q3 << ((s4.w & 1) << 4));
    }
    __syncthreads();
    unsigned* __restrict__ out = cpart + (size_t)(b * CHUNKS + chunk) * NWORDC;
    for (int i = threadIdx.x; i < NWORDC; i += 1024) out[i] = cs[i];
}

// ---------------------------------------------------------------------------
// K4: fused w + pool. grid (32, 8): b = blockIdx.x -> id%8 == b&7: reads
// cpart[b] + dinv[b] from the XCD-local L2 where K3/K2 left them.
// Block (b,c) owns nodes [c*6250,(c+1)*6250): reduce its 3125 cpart words
// (8 strided chunks) + dinv -> wlds in LDS, then pooled weighted column-sum
// (float4, 640 threads, fixed channel phase, ln += 256 strength reduction).
// ---------------------------------------------------------------------------
__global__ __launch_bounds__(PTHREADS) void pool_kernel(const unsigned* __restrict__ cpart,
                                                        const float* __restrict__ dinv,
                                                        const float* __restrict__ xg,
                                                        float* __restrict__ spart) {
    const int b = blockIdx.x, chunk = blockIdx.y;  // grid (32, 8)
    __shared__ float wlds[6250];                   // 25 KB w-slice
    __shared__ float sacc[PTHREADS / 64][10];
    const int tid = threadIdx.x;

    // ---- w-slice: w[n] = dinv*(c+dinv) for this block's 6250 nodes ----
    const int wbase = chunk * (NWORDC / 8);        // 3125 u16-pair words
    for (int li = tid; li < NWORDC / 8; li += PTHREADS) {
        const unsigned* __restrict__ p =
            cpart + (size_t)(b * CHUNKS) * NWORDC + wbase + li;
        unsigned c0 = 0, c1 = 0;
#pragma unroll
        for (int ch = 0; ch < CHUNKS; ++ch) {
            const unsigned v = p[(size_t)ch * NWORDC];
            c0 += v & 0xFFFF; c1 += v >> 16;
        }
        const int node = 2 * (wbase + li);
        const float2 d = *((const float2*)(dinv + (size_t)b * N_NODES + node));
        wlds[2 * li]     = d.x * ((float)c0 * (1.0f / QSCALE) + d.x);
        wlds[2 * li + 1] = d.y * ((float)c1 * (1.0f / QSCALE) + d.y);
    }
    const int wave = tid >> 6;
    if ((tid & 63) < 10) sacc[wave][tid & 63] = 0.0f;
    __syncthreads();

    // ---- pooled weighted column-sum from LDS w ----
    const float4* __restrict__ xg4 = (const float4*)xg;
    const int base4 = b * 125000 + chunk * 15625;  // float4 index; 4*base4 % 10 == 0
    const int r = (4 * tid) % 10;                  // element phase, fixed per lane
    int ln = (4 * tid) / 10;                       // local node; +256 per iteration
    float a0 = 0.0f, a1 = 0.0f, a2 = 0.0f, a3 = 0.0f;
    for (int j = tid; j < 15625; j += PTHREADS, ln += 256) {
        const float4 v = xg4[base4 + j];
        const float w0 = wlds[ln];
        const float w1 = (r == 8) ? wlds[ln + 1] : w0;  // r==8: z,w cross node boundary
        a0 += v.x * w0;
        a1 += v.y * w0;
        a2 += v.z * w1;
        a3 += v.w * w1;
    }
    atomicAdd(&sacc[wave][r], a0);
    atomicAdd(&sacc[wave][(r + 1) % 10], a1);
    atomicAdd(&sacc[wave][(r + 2) % 10], a2);
    atomicAdd(&sacc[wave][(r + 3) % 10], a3);
    __syncthreads();
    if (tid < 10) {
        float v = 0.0f;
#pragma unroll
        for (int wv = 0; wv < PTHREADS / 64; ++wv) v += sacc[wv][tid];
        spart[(b * CHUNKS + chunk) * 16 + tid] = v;
    }
}

// ---------------------------------------------------------------------------
// K5: reduce pool partials + tiny MLP + log_softmax(axis=0). One block.
// ---------------------------------------------------------------------------
__global__ __launch_bounds__(512) void mlp_kernel(const float* __restrict__ spart,
                           const float* __restrict__ x,
                           const float* __restrict__ W_gcn,
                           const float* __restrict__ b_gcn,
                           const float* __restrict__ W1, const float* __restrict__ b1,
                           const float* __restrict__ W2, const float* __restrict__ b2,
                           const float* __restrict__ Wo, const float* __restrict__ bo,
                           float* __restrict__ out) {
    __shared__ float ssum[32][10];
    __shared__ float h0[32][20];
    __shared__ float h1[32][80];
    __shared__ float h2[32][160];
    __shared__ float o[32][4];
    const int tid = threadIdx.x;

    for (int idx = tid; idx < 32 * 10; idx += blockDim.x) {
        const int b = idx / 10, k = idx % 10;
        float v = 0.0f;
#pragma unroll
        for (int c = 0; c < CHUNKS; ++c) v += spart[(b * CHUNKS + c) * 16 + k];
        ssum[b][k] = v;
    }
    __syncthreads();

    for (int idx = tid; idx < 32 * 20; idx += blockDim.x) {
        const int b = idx / 20, j = idx % 20;
        float v;
        if (j < 10) {
            v = 0.0f;
#pragma unroll
            for (int k = 0; k < 10; ++k) v += ssum[b][k] * W_gcn[k * 10 + j];
            v = v * (1.0f / (float)N_NODES) + b_gcn[j];
        } else {
            v = x[b * 10 + (j - 10)];
        }
        h0[b][j] = v;
    }
    __syncthreads();

    for (int idx = tid; idx < 32 * 80; idx += blockDim.x) {
        const int b = idx / 80, j = idx % 80;
        float v = b1[j];
#pragma unroll
        for (int k = 0; k < 20; ++k) v += h0[b][k] * W1[k * 80 + j];
        h1[b][j] = (v > 0.0f) ? v : 0.01f * v;
    }
    __syncthreads();

    for (int idx = tid; idx < 32 * 160; idx += blockDim.x) {
        const int b = idx / 160, j = idx % 160;
        float v = b2[j];
        for (int k = 0; k < 80; ++k) v += h1[b][k] * W2[k * 160 + j];
        h2[b][j] = (v > 0.0f) ? v : 0.01f * v;
    }
    __syncthreads();

    for (int idx = tid; idx < 32 * 4; idx += blockDim.x) {
        const int b = idx / 4, j = idx % 4;
        float v = bo[j];
        for (int k = 0; k < 160; ++k) v += h2[b][k] * Wo[k * 4 + j];
        o[b][j] = v;
    }
    __syncthreads();

    if (tid < 4) {
        float m = -1e30f;
        for (int b = 0; b < 32; ++b) m = fmaxf(m, o[b][tid]);
        float lse = 0.0f;
        for (int b = 0; b < 32; ++b) lse += expf(o[b][tid] - m);
        lse = logf(lse);
        for (int b = 0; b < 32; ++b) out[b * 4 + tid] = o[b][tid] - m - lse;
    }
}

extern "C" void kernel_launch(void* const* d_in, const int* in_sizes, int n_in,
                              void* d_out, int out_size, void* d_ws, size_t ws_size,
                              hipStream_t stream) {
    (void)in_sizes; (void)n_in; (void)out_size; (void)ws_size;
    const float* x      = (const float*)d_in[0];
    const float* gcn_x  = (const float*)d_in[1];
    const int*   ei     = (const int*)d_in[2];
    const float* W_gcn  = (const float*)d_in[3];
    const float* b_gcn  = (const float*)d_in[4];
    const float* W1     = (const float*)d_in[5];
    const float* b1     = (const float*)d_in[6];
    const float* W2     = (const float*)d_in[7];
    const float* b2     = (const float*)d_in[8];
    const float* Wo     = (const float*)d_in[9];
    const float* bo     = (const float*)d_in[10];
    float* out = (float*)d_out;

    // workspace layout (offsets in bytes):
    //   partials region [25.6 MB] @ 0     (hist uses 12.8 MB of it; cscat 25.6 MB)
    //   dinv     [32*50000 f32]   @ 25,600,000 (6.4 MB)
    //   qd8      [32*12500 u32]   @ 32,000,000 (1.6 MB)
    //   spart    [32*8*16 f32]    @ 33,600,000 (16 KB)    total ~33.6 MB
    unsigned* partials = (unsigned*)d_ws;
    float*    dinv     = (float*)((char*)d_ws + (size_t)BATCH * CHUNKS * NWORDC * 4);
    unsigned* qd8      = (unsigned*)((char*)dinv + (size_t)BATCH * N_NODES * 4);
    float*    spart    = (float*)((char*)qd8 + (size_t)BATCH * NWORD8 * 4);

    // 150 KB dynamic LDS for c-histogram (100 KB) + u8 dinv table (50 KB)
    hipFuncSetAttribute((const void*)cscat_kernel,
                        hipFuncAttributeMaxDynamicSharedMemorySize,
                        (NWORDC + NWORD8) * 4);

    {   // K1: degree histograms, batch-major grid for XCD locality
        dim3 grid(BATCH, CHUNKS);
        hist_kernel<<<grid, 1024, 0, stream>>>(ei, partials);
    }
    {   // K2: reduce -> dinv (f32), qd8 (u8 packed), batch-major grid
        dim3 grid(BATCH, (NWORD8 + 255) / 256);
        dinv_kernel<<<grid, 256, 0, stream>>>(partials, dinv, qd8);
    }
    {   // K3: full-range c-scatter, LDS-resident gather table (150 KB LDS)
        cscat_kernel<<<256, 1024, (NWORDC + NWORD8) * 4, stream>>>(ei, qd8, partials);
    }
    {   // K4: fused w + pool, batch-major grid for XCD locality
        dim3 grid(BATCH, CHUNKS);
        pool_kernel<<<grid, PTHREADS, 0, stream>>>(partials, dinv, gcn_x, spart);
    }
    mlp_kernel<<<1, 512, 0, stream>>>(spart, x, W_gcn, b_gcn, W1, b1, W2, b2, Wo, bo, out);
}